// Round 11
// baseline (276.653 us; speedup 1.0000x reference)
//
#include <hip/hip_runtime.h>
#include <hip/hip_bf16.h>

#define BS 32
#define SPAT 16384
#define NMASK 127

using short8  = __attribute__((ext_vector_type(8))) short;
using short4v = __attribute__((ext_vector_type(4))) short;
using f32x16  = __attribute__((ext_vector_type(16))) float;
using f32x4   = __attribute__((ext_vector_type(4))) float;

__device__ inline short f2bf(float f) {
  __hip_bfloat16 h = __float2bfloat16(f);
  return *reinterpret_cast<short*>(&h);
}

// ---------------- weight repack ----------------------------------------
// w2b[cob][t][c][lh][l31][8]: lane-coalesced MFMA A-fragments (1KB/fragment)
// w1a[ch][16]; w3b[c][lh][l31=t][8] lane-coalesced
__global__ __launch_bounds__(256) void prep_kernel(
    const float* __restrict__ w2, const float* __restrict__ w1,
    const float* __restrict__ w3, short* __restrict__ w2b,
    short* __restrict__ w1a, short* __restrict__ w3b) {
  int idx = blockIdx.x * 256 + threadIdx.x;
  if (idx < 36864) {
    int cob = idx / 18432, r = idx % 18432;
    int t = r / 2048, r2 = r & 2047;
    int c = r2 >> 9, lh = (r2 >> 8) & 1, l31 = (r2 >> 3) & 31, j = r2 & 7;
    int co = cob * 32 + l31, ci = c * 16 + 8 * lh + j;
    w2b[idx] = f2bf(w2[(co * 64 + ci) * 9 + t]);
  } else if (idx < 37888) {
    int j = idx - 36864;
    int ch = j >> 4, t = j & 15;
    w1a[j] = (t < 9) ? f2bf(w1[ch * 9 + t]) : (short)0;
  } else if (idx < 39936) {
    int q = idx - 37888;
    int c = q >> 9, lh = (q >> 8) & 1, l31 = (q >> 3) & 31, j = q & 7;
    int t = l31, ci = c * 16 + 8 * lh + j;
    w3b[q] = (t < 9) ? f2bf(w3[ci * 9 + t]) : (short)0;
  }
}

// ---------------- fused 3x Jacobi + residual ---------------------------
__global__ __launch_bounds__(256) void jac3_kernel(
    const float* __restrict__ uin, const float* __restrict__ f,
    float* __restrict__ u1o, float* __restrict__ u2o,
    float* __restrict__ u3o, float* __restrict__ res_ws) {
  __shared__ float As[576];   // 24x24
  __shared__ float Bs[484];   // 22x22
  __shared__ float Fs[484];   // 22x22, coords = (y0-3+i, x0-3+j)
  int tid = threadIdx.x;
  int bl = blockIdx.x >> 6, tile = blockIdx.x & 63;
  int y0 = (tile >> 3) << 4, x0 = (tile & 7) << 4;
  const float* ub = uin + ((size_t)bl << 14);
  const float* fb = f + ((size_t)bl << 14);
  for (int i = tid; i < 576; i += 256) {
    int uy = i / 24, ux = i % 24;
    As[i] = ub[(((y0 + uy - 4) & NMASK) << 7) + ((x0 + ux - 4) & NMASK)];
  }
  for (int i = tid; i < 484; i += 256) {
    int uy = i / 22, ux = i % 22;
    Fs[i] = fb[(((y0 + uy - 3) & NMASK) << 7) + ((x0 + ux - 3) & NMASK)];
  }
  __syncthreads();
  for (int i = tid; i < 484; i += 256) {
    int yy = i / 22, xx = i % 22;
    float uc = As[(yy + 1) * 24 + xx + 1];
    float ns = As[yy * 24 + xx + 1] + As[(yy + 2) * 24 + xx + 1]
             + As[(yy + 1) * 24 + xx] + As[(yy + 1) * 24 + xx + 2];
    Bs[i] = uc + Fs[i] * (1.f / 65536.f) + (ns - 4.f * uc) * 0.25f;
  }
  __syncthreads();
  {
    int y = tid >> 4, x = tid & 15;
    u1o[((size_t)bl << 14) + ((y0 + y) << 7) + x0 + x] = Bs[(y + 3) * 22 + x + 3];
  }
  for (int i = tid; i < 400; i += 256) {
    int yy = i / 20, xx = i % 20;
    float uc = Bs[(yy + 1) * 22 + xx + 1];
    float ns = Bs[yy * 22 + xx + 1] + Bs[(yy + 2) * 22 + xx + 1]
             + Bs[(yy + 1) * 22 + xx] + Bs[(yy + 1) * 22 + xx + 2];
    As[i] = uc + Fs[(yy + 1) * 22 + xx + 1] * (1.f / 65536.f)
          + (ns - 4.f * uc) * 0.25f;
  }
  __syncthreads();
  {
    int y = tid >> 4, x = tid & 15;
    u2o[((size_t)bl << 14) + ((y0 + y) << 7) + x0 + x] = As[(y + 2) * 20 + x + 2];
  }
  for (int i = tid; i < 324; i += 256) {
    int yy = i / 18, xx = i % 18;
    float uc = As[(yy + 1) * 20 + xx + 1];
    float ns = As[yy * 20 + xx + 1] + As[(yy + 2) * 20 + xx + 1]
             + As[(yy + 1) * 20 + xx] + As[(yy + 1) * 20 + xx + 2];
    Bs[i] = uc + Fs[(yy + 2) * 22 + xx + 2] * (1.f / 65536.f)
          + (ns - 4.f * uc) * 0.25f;
  }
  __syncthreads();
  {
    int y = tid >> 4, x = tid & 15;
    size_t gi = ((size_t)bl << 14) + ((y0 + y) << 7) + x0 + x;
    float uc = Bs[(y + 1) * 18 + x + 1];
    u3o[gi] = uc;
    float ns = Bs[y * 18 + x + 1] + Bs[(y + 2) * 18 + x + 1]
             + Bs[(y + 1) * 18 + x] + Bs[(y + 1) * 18 + x + 2];
    res_ws[gi] = Fs[(y + 3) * 22 + x + 3] + (ns - 4.f * uc) * 16384.f;
  }
}

// depth-1 weight pipeline, 4 frags/stage (ci half), named regs
#define WLOAD2(S, T, CB) do {                                              \
  S##0 = *reinterpret_cast<const short8*>(wb + (T) * 4096 + ((CB) + 0) * 1024); \
  S##1 = *reinterpret_cast<const short8*>(wb + (T) * 4096 + ((CB) + 1) * 1024); \
  S##2 = *reinterpret_cast<const short8*>(wb + 36864 + (T) * 4096 + ((CB) + 0) * 1024); \
  S##3 = *reinterpret_cast<const short8*>(wb + 36864 + (T) * 4096 + ((CB) + 1) * 1024); \
} while (0)
#define MM(S, T) do {                                                      \
  int toff = (((T) / 3) * 18 + ((T) % 3)) * 16;                            \
  __builtin_amdgcn_s_setprio(1);                                           \
  short8 b00 = *reinterpret_cast<const short8*>(hb0 + toff);               \
  short8 b01 = *reinterpret_cast<const short8*>(hb0 + 576 + toff);         \
  acc00 = __builtin_amdgcn_mfma_f32_32x32x16_bf16(S##0, b00, acc00, 0,0,0);\
  acc01 = __builtin_amdgcn_mfma_f32_32x32x16_bf16(S##0, b01, acc01, 0,0,0);\
  acc10 = __builtin_amdgcn_mfma_f32_32x32x16_bf16(S##2, b00, acc10, 0,0,0);\
  acc11 = __builtin_amdgcn_mfma_f32_32x32x16_bf16(S##2, b01, acc11, 0,0,0);\
  short8 b10 = *reinterpret_cast<const short8*>(hb0 + 10368 + toff);       \
  short8 b11 = *reinterpret_cast<const short8*>(hb0 + 10944 + toff);       \
  acc00 = __builtin_amdgcn_mfma_f32_32x32x16_bf16(S##1, b10, acc00, 0,0,0);\
  acc01 = __builtin_amdgcn_mfma_f32_32x32x16_bf16(S##1, b11, acc01, 0,0,0);\
  acc10 = __builtin_amdgcn_mfma_f32_32x32x16_bf16(S##3, b10, acc10, 0,0,0);\
  acc11 = __builtin_amdgcn_mfma_f32_32x32x16_bf16(S##3, b11, acc11, 0,0,0);\
  __builtin_amdgcn_s_setprio(0);                                           \
} while (0)

// conv1 half-pass: computes 32 channels (CH0..CH0+31) into h1 cgroups 0-3
#define CONV1_HALF(CH0) do {                                               \
  short8 a1 = *reinterpret_cast<const short8*>(&w1a[((CH0) + l31) * 16 + 8 * lh]); \
  for (int g = wv; g < 11; g += 4) {                                       \
    int pos = g * 32 + l31;                                                \
    short8 bf = {};                                                        \
    if (pos < 324) {                                                       \
      int yy = pos / 18, xx = pos % 18;                                    \
      if (lh == 0) {                                                       \
        for (int t = 0; t < 8; ++t)                                        \
          bf[t] = f2bf(res_s[(yy + t / 3) * 20 + xx + t % 3]);             \
      } else {                                                             \
        bf[0] = f2bf(res_s[(yy + 2) * 20 + xx + 2]);                       \
      }                                                                    \
    }                                                                      \
    f32x16 a;                                                              \
    for (int r = 0; r < 16; ++r) a[r] = 0.f;                               \
    a = __builtin_amdgcn_mfma_f32_32x32x16_bf16(a1, bf, a, 0, 0, 0);       \
    if (pos < 324) {                                                       \
      for (int q = 0; q < 4; ++q) {                                        \
        f32x4 bv = *reinterpret_cast<const f32x4*>(&b1v[(CH0) + 8 * q + 4 * lh]); \
        short4v o;                                                         \
        for (int j = 0; j < 4; ++j) {                                      \
          float v = a[4 * q + j] + bv[j];                                  \
          o[j] = f2bf(v > 0.f ? v : 0.f);                                  \
        }                                                                  \
        *reinterpret_cast<short4v*>(h1 + (q * 324 + pos) * 16 + 8 * lh) = o; \
      }                                                                    \
    }                                                                      \
  }                                                                        \
} while (0)

// ---------------- fused conv1 + conv2 + depthwise-conv3 (all MFMA) -----
// 256 threads (4 waves); K-split over ci halves: h1 half-buffer -> LDS 32KB
// -> 4 blocks/CU (16 waves/CU). conv2 weights depth-1 (4 frags/stage).
__global__ __launch_bounds__(256, 4) void mlstep_a(
    const float* __restrict__ res_ws,
    const short* __restrict__ w1a, const float* __restrict__ b1v,
    const short* __restrict__ w2b, const float* __restrict__ b2v,
    const short* __restrict__ w3b, float* __restrict__ D_ws,
    int b0, int BC) {
  __shared__ __align__(16) char lds[32768];
  char* h1 = lds;                        // [4cg][324][16B] = 20736 B per pass
  float* res_s = (float*)(lds + 20736);  // 400 floats (dead before h2t)
  short* h2t = (short*)lds;              // [8cg][256][8] = 32768 B (epilogue)
  int tid = threadIdx.x;
  int bl = blockIdx.x >> 6;
  int tile = blockIdx.x & 63;
  int y0 = (tile >> 3) << 4, x0 = (tile & 7) << 4;
  const float* rb = res_ws + ((size_t)(b0 + bl) << 14);

  for (int i = tid; i < 400; i += 256) {
    int ry = i / 20, rx = i % 20;
    res_s[i] = rb[(((y0 + ry - 2) & NMASK) << 7) + ((x0 + rx - 2) & NMASK)];
  }

  int lane = tid & 63, wv = tid >> 6;  // wv in 0..3
  int l31 = lane & 31, lh = lane >> 5;
  const char* wb = (const char*)w2b + lane * 16;

  short8 wP0, wP1, wP2, wP3, wQ0, wQ1, wQ2, wQ3;
  WLOAD2(wP, 0, 0);  // pass-A stage 0 (hides under res stage + conv1-A)
  __syncthreads();

  const char* hb0;
  {
    int px0 = (wv << 6) + l31;
    hb0 = h1 + lh * 5184 + ((px0 >> 4) * 18 + (px0 & 15)) * 16;
    // px1 = px0+32 is exactly 2 rows down -> hb0 + 2*18*16 = +576
  }
  f32x16 acc00, acc01, acc10, acc11;  // [cob][nt]
#pragma unroll
  for (int r = 0; r < 16; ++r) {
    acc00[r] = 0.f; acc01[r] = 0.f; acc10[r] = 0.f; acc11[r] = 0.f;
  }

  // ================= pass A: ci 0..31 =================
  CONV1_HALF(0);
  __syncthreads();
  WLOAD2(wQ, 1, 0); MM(wP, 0);
  WLOAD2(wP, 2, 0); MM(wQ, 1);
  WLOAD2(wQ, 3, 0); MM(wP, 2);
  WLOAD2(wP, 4, 0); MM(wQ, 3);
  WLOAD2(wQ, 5, 0); MM(wP, 4);
  WLOAD2(wP, 6, 0); MM(wQ, 5);
  WLOAD2(wQ, 7, 0); MM(wP, 6);
  WLOAD2(wP, 8, 0); MM(wQ, 7);
  WLOAD2(wQ, 0, 2); MM(wP, 8);  // prefetch pass-B stage 0
  __syncthreads();

  // ================= pass B: ci 32..63 =================
  CONV1_HALF(32);
  __syncthreads();
  WLOAD2(wP, 1, 2); MM(wQ, 0);
  WLOAD2(wQ, 2, 2); MM(wP, 1);
  WLOAD2(wP, 3, 2); MM(wQ, 2);
  WLOAD2(wQ, 4, 2); MM(wP, 3);
  WLOAD2(wP, 5, 2); MM(wQ, 4);
  WLOAD2(wQ, 6, 2); MM(wP, 5);
  WLOAD2(wP, 7, 2); MM(wQ, 6);
  WLOAD2(wQ, 8, 2); MM(wP, 7);
  MM(wQ, 8);
  __syncthreads();  // all conv2 reads of h1 done -> reuse LDS as h2t

  // h2 (ReLU+bias, bf16) -> LDS cg-major [cg][px][8]
#pragma unroll
  for (int nt = 0; nt < 2; ++nt) {
    int px = (wv << 6) + (nt << 5) + l31;
#pragma unroll
    for (int cb = 0; cb < 2; ++cb) {
      const f32x16& a = cb ? (nt ? acc11 : acc10) : (nt ? acc01 : acc00);
#pragma unroll
      for (int q = 0; q < 4; ++q) {
        int ch0 = cb * 32 + 8 * q + 4 * lh;
        f32x4 bv = *reinterpret_cast<const f32x4*>(&b2v[ch0]);
        short4v o;
#pragma unroll
        for (int j = 0; j < 4; ++j) {
          float v = a[4 * q + j] + bv[j];
          o[j] = f2bf(v > 0.f ? v : 0.f);
        }
        int cg = cb * 4 + q;
        *reinterpret_cast<short4v*>(&h2t[(cg * 256 + px) * 8 + 4 * lh]) = o;
      }
    }
  }
  // depthwise conv3 — wave-local px, no barrier needed
  short8 af30 = *reinterpret_cast<const short8*>((const char*)w3b + lane * 16);
  short8 af31 = *reinterpret_cast<const short8*>((const char*)w3b + 1024 + lane * 16);
  short8 af32 = *reinterpret_cast<const short8*>((const char*)w3b + 2048 + lane * 16);
  short8 af33 = *reinterpret_cast<const short8*>((const char*)w3b + 3072 + lane * 16);
#pragma unroll
  for (int nt = 0; nt < 2; ++nt) {
    int pxb = (wv << 6) + (nt << 5);
    f32x16 d;
#pragma unroll
    for (int r = 0; r < 16; ++r) d[r] = 0.f;
    __builtin_amdgcn_s_setprio(1);
    {
      short8 bf;
      bf = *reinterpret_cast<const short8*>(
          (const char*)h2t + ((0 + lh) * 256 + pxb + l31) * 16);
      d = __builtin_amdgcn_mfma_f32_32x32x16_bf16(af30, bf, d, 0, 0, 0);
      bf = *reinterpret_cast<const short8*>(
          (const char*)h2t + ((2 + lh) * 256 + pxb + l31) * 16);
      d = __builtin_amdgcn_mfma_f32_32x32x16_bf16(af31, bf, d, 0, 0, 0);
      bf = *reinterpret_cast<const short8*>(
          (const char*)h2t + ((4 + lh) * 256 + pxb + l31) * 16);
      d = __builtin_amdgcn_mfma_f32_32x32x16_bf16(af32, bf, d, 0, 0, 0);
      bf = *reinterpret_cast<const short8*>(
          (const char*)h2t + ((6 + lh) * 256 + pxb + l31) * 16);
      d = __builtin_amdgcn_mfma_f32_32x32x16_bf16(af33, bf, d, 0, 0, 0);
    }
    __builtin_amdgcn_s_setprio(0);
    int px = pxb + l31;
    int gpx = ((y0 + (px >> 4)) << 7) + x0 + (px & 15);
    if (lh == 0) {
#pragma unroll
      for (int r = 0; r < 4; ++r)
        D_ws[((size_t)(r * BC + bl) << 14) + gpx] = d[r];
      D_ws[((size_t)(8 * BC + bl) << 14) + gpx] = d[4];
    } else {
#pragma unroll
      for (int r = 0; r < 4; ++r)
        D_ws[((size_t)((4 + r) * BC + bl) << 14) + gpx] = d[r];
    }
  }
}

// ---------------- conv3 shift-sum + u update (memory-bound) -------------
__global__ __launch_bounds__(256) void mlstep_b(
    const float* __restrict__ D_ws, const float* __restrict__ b3,
    const float* __restrict__ uprev, float* __restrict__ uout,
    int b0, int BC) {
  int idx = blockIdx.x * 256 + threadIdx.x;
  int bl = idx >> 14;
  int rem = idx & (SPAT - 1);
  int y = rem >> 7, x = rem & NMASK;
  float acc = b3[0];
#pragma unroll
  for (int t = 0; t < 9; ++t) {
    int yy = (y + t / 3 - 1) & NMASK;
    int xx = (x + t % 3 - 1) & NMASK;
    acc += D_ws[((size_t)(t * BC + bl) << 14) + (yy << 7) + xx];
  }
  size_t g = ((size_t)(b0 + bl) << 14) + rem;
  uout[g] = uprev[g] + acc;
}

// ---------------- routing scores ----------------------------------------
__global__ void scores_kernel(float* __restrict__ s) {
  int i = blockIdx.x * 256 + threadIdx.x;
  if (i < 8 * BS * 2) {
    int it = i >> 6;
    int k = i & 1;
    bool ml = (it & 3) == 3;
    s[i] = ml ? (float)k : (float)(1 - k);
  }
}

extern "C" void kernel_launch(void* const* d_in, const int* in_sizes, int n_in,
                              void* d_out, int out_size, void* d_ws,
                              size_t ws_size, hipStream_t stream) {
  (void)in_sizes; (void)n_in; (void)out_size;
  const float* f  = (const float*)d_in[0];
  const float* u0 = (const float*)d_in[1];
  const float* w1 = (const float*)d_in[2];
  const float* b1 = (const float*)d_in[3];
  const float* w2 = (const float*)d_in[4];
  const float* b2 = (const float*)d_in[5];
  const float* w3 = (const float*)d_in[6];
  const float* b3 = (const float*)d_in[7];

  float* preds  = (float*)d_out;                  // [8][32][128][128]
  float* scores = preds + (size_t)8 * BS * SPAT;  // [8][32][2]

  short* w2b = (short*)d_ws;                       // 73728 B
  short* w1a = w2b + 36864;                        // 2048 B
  short* w3b = w1a + 1024;                         // 4096 B
  float* res_ws = (float*)(w3b + 2048);            // 2 MB
  float* D_ws = res_ws + (size_t)BS * SPAT;        // 9*BC*64KB
  size_t fixed = (size_t)(36864 + 1024 + 2048) * 2 + (size_t)BS * SPAT * 4;
  size_t avail = ws_size > fixed ? ws_size - fixed : 0;
  int BC = 32;
  while (BC > 1 && (size_t)BC * ((size_t)9 * SPAT * 4) > avail) BC >>= 1;

  prep_kernel<<<156, 256, 0, stream>>>(w2, w1, w3, w2b, w1a, w3b);

  for (int p = 0; p < 2; ++p) {
    int it = 4 * p;
    const float* up = (p == 0) ? u0 : preds + (size_t)3 * BS * SPAT;
    float* u1o = preds + (size_t)(it + 0) * BS * SPAT;
    float* u2o = preds + (size_t)(it + 1) * BS * SPAT;
    float* u3o = preds + (size_t)(it + 2) * BS * SPAT;
    float* umo = preds + (size_t)(it + 3) * BS * SPAT;
    jac3_kernel<<<BS * 64, 256, 0, stream>>>(up, f, u1o, u2o, u3o, res_ws);
    for (int b0 = 0; b0 < BS; b0 += BC) {
      mlstep_a<<<BC * 64, 256, 0, stream>>>(res_ws, w1a, b1, w2b, b2, w3b,
                                            D_ws, b0, BC);
      mlstep_b<<<BC * SPAT / 256, 256, 0, stream>>>(D_ws, b3, u3o, umo, b0, BC);
    }
  }
  scores_kernel<<<2, 256, 0, stream>>>(scores);
}

// Round 12
// 126.930 us; speedup vs baseline: 2.1796x; 2.1796x over previous
//
#include <hip/hip_runtime.h>
#include <hip/hip_bf16.h>

#define BS 32
#define SPAT 16384
#define NMASK 127

using short8  = __attribute__((ext_vector_type(8))) short;
using short4v = __attribute__((ext_vector_type(4))) short;
using f32x16  = __attribute__((ext_vector_type(16))) float;
using f32x4   = __attribute__((ext_vector_type(4))) float;

__device__ inline short f2bf(float f) {
  __hip_bfloat16 h = __float2bfloat16(f);
  return *reinterpret_cast<short*>(&h);
}

// ---------------- weight repack ----------------------------------------
// w2b[cob][t][c][lh][l31][8]: lane-coalesced MFMA A-fragments (1KB/fragment)
// w1a[ch][16]; w3b[c][lh][l31=t][8] lane-coalesced
__global__ __launch_bounds__(256) void prep_kernel(
    const float* __restrict__ w2, const float* __restrict__ w1,
    const float* __restrict__ w3, short* __restrict__ w2b,
    short* __restrict__ w1a, short* __restrict__ w3b) {
  int idx = blockIdx.x * 256 + threadIdx.x;
  if (idx < 36864) {
    int cob = idx / 18432, r = idx % 18432;
    int t = r / 2048, r2 = r & 2047;
    int c = r2 >> 9, lh = (r2 >> 8) & 1, l31 = (r2 >> 3) & 31, j = r2 & 7;
    int co = cob * 32 + l31, ci = c * 16 + 8 * lh + j;
    w2b[idx] = f2bf(w2[(co * 64 + ci) * 9 + t]);
  } else if (idx < 37888) {
    int j = idx - 36864;
    int ch = j >> 4, t = j & 15;
    w1a[j] = (t < 9) ? f2bf(w1[ch * 9 + t]) : (short)0;
  } else if (idx < 39936) {
    int q = idx - 37888;
    int c = q >> 9, lh = (q >> 8) & 1, l31 = (q >> 3) & 31, j = q & 7;
    int t = l31, ci = c * 16 + 8 * lh + j;
    w3b[q] = (t < 9) ? f2bf(w3[ci * 9 + t]) : (short)0;
  }
}

// ---------------- fused 3x Jacobi + residual ---------------------------
__global__ __launch_bounds__(256) void jac3_kernel(
    const float* __restrict__ uin, const float* __restrict__ f,
    float* __restrict__ u1o, float* __restrict__ u2o,
    float* __restrict__ u3o, float* __restrict__ res_ws) {
  __shared__ float As[576];   // 24x24
  __shared__ float Bs[484];   // 22x22
  __shared__ float Fs[484];   // 22x22, coords = (y0-3+i, x0-3+j)
  int tid = threadIdx.x;
  int bl = blockIdx.x >> 6, tile = blockIdx.x & 63;
  int y0 = (tile >> 3) << 4, x0 = (tile & 7) << 4;
  const float* ub = uin + ((size_t)bl << 14);
  const float* fb = f + ((size_t)bl << 14);
  for (int i = tid; i < 576; i += 256) {
    int uy = i / 24, ux = i % 24;
    As[i] = ub[(((y0 + uy - 4) & NMASK) << 7) + ((x0 + ux - 4) & NMASK)];
  }
  for (int i = tid; i < 484; i += 256) {
    int uy = i / 22, ux = i % 22;
    Fs[i] = fb[(((y0 + uy - 3) & NMASK) << 7) + ((x0 + ux - 3) & NMASK)];
  }
  __syncthreads();
  for (int i = tid; i < 484; i += 256) {
    int yy = i / 22, xx = i % 22;
    float uc = As[(yy + 1) * 24 + xx + 1];
    float ns = As[yy * 24 + xx + 1] + As[(yy + 2) * 24 + xx + 1]
             + As[(yy + 1) * 24 + xx] + As[(yy + 1) * 24 + xx + 2];
    Bs[i] = uc + Fs[i] * (1.f / 65536.f) + (ns - 4.f * uc) * 0.25f;
  }
  __syncthreads();
  {
    int y = tid >> 4, x = tid & 15;
    u1o[((size_t)bl << 14) + ((y0 + y) << 7) + x0 + x] = Bs[(y + 3) * 22 + x + 3];
  }
  for (int i = tid; i < 400; i += 256) {
    int yy = i / 20, xx = i % 20;
    float uc = Bs[(yy + 1) * 22 + xx + 1];
    float ns = Bs[yy * 22 + xx + 1] + Bs[(yy + 2) * 22 + xx + 1]
             + Bs[(yy + 1) * 22 + xx] + Bs[(yy + 1) * 22 + xx + 2];
    As[i] = uc + Fs[(yy + 1) * 22 + xx + 1] * (1.f / 65536.f)
          + (ns - 4.f * uc) * 0.25f;
  }
  __syncthreads();
  {
    int y = tid >> 4, x = tid & 15;
    u2o[((size_t)bl << 14) + ((y0 + y) << 7) + x0 + x] = As[(y + 2) * 20 + x + 2];
  }
  for (int i = tid; i < 324; i += 256) {
    int yy = i / 18, xx = i % 18;
    float uc = As[(yy + 1) * 20 + xx + 1];
    float ns = As[yy * 20 + xx + 1] + As[(yy + 2) * 20 + xx + 1]
             + As[(yy + 1) * 20 + xx] + As[(yy + 1) * 20 + xx + 2];
    Bs[i] = uc + Fs[(yy + 2) * 22 + xx + 2] * (1.f / 65536.f)
          + (ns - 4.f * uc) * 0.25f;
  }
  __syncthreads();
  {
    int y = tid >> 4, x = tid & 15;
    size_t gi = ((size_t)bl << 14) + ((y0 + y) << 7) + x0 + x;
    float uc = Bs[(y + 1) * 18 + x + 1];
    u3o[gi] = uc;
    float ns = Bs[y * 18 + x + 1] + Bs[(y + 2) * 18 + x + 1]
             + Bs[(y + 1) * 18 + x] + Bs[(y + 1) * 18 + x + 2];
    res_ws[gi] = Fs[(y + 3) * 22 + x + 3] + (ns - 4.f * uc) * 16384.f;
  }
}

// half-stage pipeline macros: half-stage = (t, c-pair P); 4 named frags,
// 8 MFMAs, 4 B-reads. 4 rotating buffers -> prefetch distance 3 (192cy).
#define WDECLH(S) short8 S##0, S##1, S##2, S##3
#define WLOADH(S, T, P) do {                                                \
  S##0 = *reinterpret_cast<const short8*>(wb + ((T) * 4 + 2 * (P) + 0) * 1024); \
  S##1 = *reinterpret_cast<const short8*>(wb + ((T) * 4 + 2 * (P) + 1) * 1024); \
  S##2 = *reinterpret_cast<const short8*>(wb + 36864 + ((T) * 4 + 2 * (P) + 0) * 1024); \
  S##3 = *reinterpret_cast<const short8*>(wb + 36864 + ((T) * 4 + 2 * (P) + 1) * 1024); \
} while (0)
#define MMH(S, T, P) do {                                                   \
  int toff = (((T) / 3) * 18 + ((T) % 3)) * 16;                             \
  __builtin_amdgcn_s_setprio(1);                                            \
  short8 b0 = *reinterpret_cast<const short8*>(hb0 + (2 * (P)) * 10368 + toff); \
  short8 b1 = *reinterpret_cast<const short8*>(hb1 + (2 * (P)) * 10368 + toff); \
  acc00 = __builtin_amdgcn_mfma_f32_32x32x16_bf16(S##0, b0, acc00, 0, 0, 0);\
  acc01 = __builtin_amdgcn_mfma_f32_32x32x16_bf16(S##0, b1, acc01, 0, 0, 0);\
  acc10 = __builtin_amdgcn_mfma_f32_32x32x16_bf16(S##2, b0, acc10, 0, 0, 0);\
  acc11 = __builtin_amdgcn_mfma_f32_32x32x16_bf16(S##2, b1, acc11, 0, 0, 0);\
  short8 b2 = *reinterpret_cast<const short8*>(hb0 + (2 * (P) + 1) * 10368 + toff); \
  short8 b3 = *reinterpret_cast<const short8*>(hb1 + (2 * (P) + 1) * 10368 + toff); \
  acc00 = __builtin_amdgcn_mfma_f32_32x32x16_bf16(S##1, b2, acc00, 0, 0, 0);\
  acc01 = __builtin_amdgcn_mfma_f32_32x32x16_bf16(S##1, b3, acc01, 0, 0, 0);\
  acc10 = __builtin_amdgcn_mfma_f32_32x32x16_bf16(S##3, b2, acc10, 0, 0, 0);\
  acc11 = __builtin_amdgcn_mfma_f32_32x32x16_bf16(S##3, b3, acc11, 0, 0, 0);\
  __builtin_amdgcn_s_setprio(0);                                            \
} while (0)

// ---------------- fused conv1 + conv2 + depthwise-conv3 (all MFMA) -----
// 256 threads (4 waves); wave wv owns px [wv*64, wv*64+64), all 64 co.
// conv2 weights: half-stage pipeline, distance 3, 16 frags total (= R8's
// register footprint, +50% latency coverage).
__global__ __launch_bounds__(256, 3) void mlstep_a(
    const float* __restrict__ res_ws,
    const short* __restrict__ w1a, const float* __restrict__ b1v,
    const short* __restrict__ w2b, const float* __restrict__ b2v,
    const short* __restrict__ w3b, float* __restrict__ D_ws,
    int b0, int BC) {
  __shared__ __align__(16) short h1g[8 * 324 * 8];  // reused as h2t [8][256][8]
  __shared__ float res_s[400];                      // 20x20, halo 2
  int tid = threadIdx.x;
  int bl = blockIdx.x >> 6;
  int tile = blockIdx.x & 63;
  int y0 = (tile >> 3) << 4, x0 = (tile & 7) << 4;
  const float* rb = res_ws + ((size_t)(b0 + bl) << 14);

  for (int i = tid; i < 400; i += 256) {
    int ry = i / 20, rx = i % 20;
    res_s[i] = rb[(((y0 + ry - 2) & NMASK) << 7) + ((x0 + rx - 2) & NMASK)];
  }

  int lane = tid & 63, wv = tid >> 6;  // wv in 0..3
  int l31 = lane & 31, lh = lane >> 5;

  // ---- pre-issue first 3 half-stages (latency hides under conv1) --------
  const char* wb = (const char*)w2b + lane * 16;
  WDECLH(wR); WDECLH(wS); WDECLH(wT); WDECLH(wU);
  WLOADH(wR, 0, 0);
  WLOADH(wS, 0, 1);
  WLOADH(wT, 1, 0);
  __syncthreads();

  // conv1 via MFMA (11 pos-groups over 4 waves); B-frag built in registers
  {
    short8 a1lo = *reinterpret_cast<const short8*>(&w1a[l31 * 16 + 8 * lh]);
    short8 a1hi = *reinterpret_cast<const short8*>(&w1a[(32 + l31) * 16 + 8 * lh]);
    for (int g = wv; g < 11; g += 4) {
      int pos = g * 32 + l31;
      short8 bf = {};
      if (pos < 324) {
        int yy = pos / 18, xx = pos % 18;
        if (lh == 0) {
#pragma unroll
          for (int t = 0; t < 8; ++t)
            bf[t] = f2bf(res_s[(yy + t / 3) * 20 + xx + t % 3]);
        } else {
          bf[0] = f2bf(res_s[(yy + 2) * 20 + xx + 2]);
        }
      }
      f32x16 acc0, acc1;
#pragma unroll
      for (int r = 0; r < 16; ++r) { acc0[r] = 0.f; acc1[r] = 0.f; }
      acc0 = __builtin_amdgcn_mfma_f32_32x32x16_bf16(a1lo, bf, acc0, 0, 0, 0);
      acc1 = __builtin_amdgcn_mfma_f32_32x32x16_bf16(a1hi, bf, acc1, 0, 0, 0);
      if (pos < 324) {
#pragma unroll
        for (int q = 0; q < 4; ++q) {
          f32x4 bv0 = *reinterpret_cast<const f32x4*>(&b1v[8 * q + 4 * lh]);
          f32x4 bv1 = *reinterpret_cast<const f32x4*>(&b1v[32 + 8 * q + 4 * lh]);
          short4v o0, o1;
#pragma unroll
          for (int j = 0; j < 4; ++j) {
            float v0 = acc0[4 * q + j] + bv0[j];
            float v1 = acc1[4 * q + j] + bv1[j];
            o0[j] = f2bf(v0 > 0.f ? v0 : 0.f);
            o1[j] = f2bf(v1 > 0.f ? v1 : 0.f);
          }
          *reinterpret_cast<short4v*>(
              (char*)h1g + (q * 324 + pos) * 16 + 8 * lh) = o0;
          *reinterpret_cast<short4v*>(
              (char*)h1g + ((4 + q) * 324 + pos) * 16 + 8 * lh) = o1;
        }
      }
    }
  }
  __syncthreads();

  // conv2: half-stage pipeline, 18 half-stages, 4 rotating buffers
  {
    const char* hb0;
    const char* hb1;
    {
      int px0 = (wv << 6) + l31;
      int px1 = (wv << 6) + 32 + l31;
      hb0 = (const char*)h1g + lh * 5184 + ((px0 >> 4) * 18 + (px0 & 15)) * 16;
      hb1 = (const char*)h1g + lh * 5184 + ((px1 >> 4) * 18 + (px1 & 15)) * 16;
    }
    f32x16 acc00, acc01, acc10, acc11;  // [cob][nt]
#pragma unroll
    for (int r = 0; r < 16; ++r) {
      acc00[r] = 0.f; acc01[r] = 0.f; acc10[r] = 0.f; acc11[r] = 0.f;
    }
    WLOADH(wU, 1, 1); MMH(wR, 0, 0);
    WLOADH(wR, 2, 0); MMH(wS, 0, 1);
    WLOADH(wS, 2, 1); MMH(wT, 1, 0);
    WLOADH(wT, 3, 0); MMH(wU, 1, 1);
    WLOADH(wU, 3, 1); MMH(wR, 2, 0);
    WLOADH(wR, 4, 0); MMH(wS, 2, 1);
    WLOADH(wS, 4, 1); MMH(wT, 3, 0);
    WLOADH(wT, 5, 0); MMH(wU, 3, 1);
    WLOADH(wU, 5, 1); MMH(wR, 4, 0);
    WLOADH(wR, 6, 0); MMH(wS, 4, 1);
    WLOADH(wS, 6, 1); MMH(wT, 5, 0);
    WLOADH(wT, 7, 0); MMH(wU, 5, 1);
    WLOADH(wU, 7, 1); MMH(wR, 6, 0);
    WLOADH(wR, 8, 0); MMH(wS, 6, 1);
    WLOADH(wS, 8, 1); MMH(wT, 7, 0);
    MMH(wU, 7, 1);
    MMH(wR, 8, 0);
    MMH(wS, 8, 1);
    __syncthreads();  // conv2 reads of h1g done -> reuse as h2t

    // h2 (ReLU+bias, bf16) -> LDS cg-major [cg][px][8]
    short* h2t = h1g;
#pragma unroll
    for (int nt = 0; nt < 2; ++nt) {
      int px = (wv << 6) + (nt << 5) + l31;
#pragma unroll
      for (int cb = 0; cb < 2; ++cb) {
        const f32x16& a = cb ? (nt ? acc11 : acc10) : (nt ? acc01 : acc00);
#pragma unroll
        for (int q = 0; q < 4; ++q) {
          int ch0 = cb * 32 + 8 * q + 4 * lh;
          f32x4 bv = *reinterpret_cast<const f32x4*>(&b2v[ch0]);
          short4v o;
#pragma unroll
          for (int j = 0; j < 4; ++j) {
            float v = a[4 * q + j] + bv[j];
            o[j] = f2bf(v > 0.f ? v : 0.f);
          }
          int cg = cb * 4 + q;
          *reinterpret_cast<short4v*>(&h2t[(cg * 256 + px) * 8 + 4 * lh]) = o;
        }
      }
    }
    // depthwise conv3 — wave-local px, no barrier needed
    short8 af30 = *reinterpret_cast<const short8*>((const char*)w3b + lane * 16);
    short8 af31 = *reinterpret_cast<const short8*>((const char*)w3b + 1024 + lane * 16);
    short8 af32 = *reinterpret_cast<const short8*>((const char*)w3b + 2048 + lane * 16);
    short8 af33 = *reinterpret_cast<const short8*>((const char*)w3b + 3072 + lane * 16);
#pragma unroll
    for (int nt = 0; nt < 2; ++nt) {
      int pxb = (wv << 6) + (nt << 5);
      f32x16 d;
#pragma unroll
      for (int r = 0; r < 16; ++r) d[r] = 0.f;
      __builtin_amdgcn_s_setprio(1);
      {
        short8 bf;
        bf = *reinterpret_cast<const short8*>(
            (const char*)h2t + ((0 + lh) * 256 + pxb + l31) * 16);
        d = __builtin_amdgcn_mfma_f32_32x32x16_bf16(af30, bf, d, 0, 0, 0);
        bf = *reinterpret_cast<const short8*>(
            (const char*)h2t + ((2 + lh) * 256 + pxb + l31) * 16);
        d = __builtin_amdgcn_mfma_f32_32x32x16_bf16(af31, bf, d, 0, 0, 0);
        bf = *reinterpret_cast<const short8*>(
            (const char*)h2t + ((4 + lh) * 256 + pxb + l31) * 16);
        d = __builtin_amdgcn_mfma_f32_32x32x16_bf16(af32, bf, d, 0, 0, 0);
        bf = *reinterpret_cast<const short8*>(
            (const char*)h2t + ((6 + lh) * 256 + pxb + l31) * 16);
        d = __builtin_amdgcn_mfma_f32_32x32x16_bf16(af33, bf, d, 0, 0, 0);
      }
      __builtin_amdgcn_s_setprio(0);
      int px = pxb + l31;
      int gpx = ((y0 + (px >> 4)) << 7) + x0 + (px & 15);
      if (lh == 0) {
#pragma unroll
        for (int r = 0; r < 4; ++r)
          D_ws[((size_t)(r * BC + bl) << 14) + gpx] = d[r];
        D_ws[((size_t)(8 * BC + bl) << 14) + gpx] = d[4];
      } else {
#pragma unroll
        for (int r = 0; r < 4; ++r)
          D_ws[((size_t)((4 + r) * BC + bl) << 14) + gpx] = d[r];
      }
    }
  }
}

// ---------------- conv3 shift-sum + u update (memory-bound) -------------
__global__ __launch_bounds__(256) void mlstep_b(
    const float* __restrict__ D_ws, const float* __restrict__ b3,
    const float* __restrict__ uprev, float* __restrict__ uout,
    int b0, int BC) {
  int idx = blockIdx.x * 256 + threadIdx.x;
  int bl = idx >> 14;
  int rem = idx & (SPAT - 1);
  int y = rem >> 7, x = rem & NMASK;
  float acc = b3[0];
#pragma unroll
  for (int t = 0; t < 9; ++t) {
    int yy = (y + t / 3 - 1) & NMASK;
    int xx = (x + t % 3 - 1) & NMASK;
    acc += D_ws[((size_t)(t * BC + bl) << 14) + (yy << 7) + xx];
  }
  size_t g = ((size_t)(b0 + bl) << 14) + rem;
  uout[g] = uprev[g] + acc;
}

// ---------------- routing scores ----------------------------------------
__global__ void scores_kernel(float* __restrict__ s) {
  int i = blockIdx.x * 256 + threadIdx.x;
  if (i < 8 * BS * 2) {
    int it = i >> 6;
    int k = i & 1;
    bool ml = (it & 3) == 3;
    s[i] = ml ? (float)k : (float)(1 - k);
  }
}

extern "C" void kernel_launch(void* const* d_in, const int* in_sizes, int n_in,
                              void* d_out, int out_size, void* d_ws,
                              size_t ws_size, hipStream_t stream) {
  (void)in_sizes; (void)n_in; (void)out_size;
  const float* f  = (const float*)d_in[0];
  const float* u0 = (const float*)d_in[1];
  const float* w1 = (const float*)d_in[2];
  const float* b1 = (const float*)d_in[3];
  const float* w2 = (const float*)d_in[4];
  const float* b2 = (const float*)d_in[5];
  const float* w3 = (const float*)d_in[6];
  const float* b3 = (const float*)d_in[7];

  float* preds  = (float*)d_out;                  // [8][32][128][128]
  float* scores = preds + (size_t)8 * BS * SPAT;  // [8][32][2]

  short* w2b = (short*)d_ws;                       // 73728 B
  short* w1a = w2b + 36864;                        // 2048 B
  short* w3b = w1a + 1024;                         // 4096 B
  float* res_ws = (float*)(w3b + 2048);            // 2 MB
  float* D_ws = res_ws + (size_t)BS * SPAT;        // 9*BC*64KB
  size_t fixed = (size_t)(36864 + 1024 + 2048) * 2 + (size_t)BS * SPAT * 4;
  size_t avail = ws_size > fixed ? ws_size - fixed : 0;
  int BC = 32;
  while (BC > 1 && (size_t)BC * ((size_t)9 * SPAT * 4) > avail) BC >>= 1;

  prep_kernel<<<156, 256, 0, stream>>>(w2, w1, w3, w2b, w1a, w3b);

  for (int p = 0; p < 2; ++p) {
    int it = 4 * p;
    const float* up = (p == 0) ? u0 : preds + (size_t)3 * BS * SPAT;
    float* u1o = preds + (size_t)(it + 0) * BS * SPAT;
    float* u2o = preds + (size_t)(it + 1) * BS * SPAT;
    float* u3o = preds + (size_t)(it + 2) * BS * SPAT;
    float* umo = preds + (size_t)(it + 3) * BS * SPAT;
    jac3_kernel<<<BS * 64, 256, 0, stream>>>(up, f, u1o, u2o, u3o, res_ws);
    for (int b0 = 0; b0 < BS; b0 += BC) {
      mlstep_a<<<BC * 64, 256, 0, stream>>>(res_ws, w1a, b1, w2b, b2, w3b,
                                            D_ws, b0, BC);
      mlstep_b<<<BC * SPAT / 256, 256, 0, stream>>>(D_ws, b3, u3o, umo, b0, BC);
    }
  }
  scores_kernel<<<2, 256, 0, stream>>>(scores);
}

// Round 13
// 125.233 us; speedup vs baseline: 2.2091x; 1.0136x over previous
//
#include <hip/hip_runtime.h>
#include <hip/hip_bf16.h>

#define BS 32
#define SPAT 16384
#define NMASK 127

using short8  = __attribute__((ext_vector_type(8))) short;
using short4v = __attribute__((ext_vector_type(4))) short;
using f32x16  = __attribute__((ext_vector_type(16))) float;
using f32x4   = __attribute__((ext_vector_type(4))) float;

__device__ inline short f2bf(float f) {
  __hip_bfloat16 h = __float2bfloat16(f);
  return *reinterpret_cast<short*>(&h);
}

// ---------------- weight repack ----------------------------------------
// w2b[cob][t][c][lh][l31][8]: lane-coalesced MFMA A-fragments (1KB/fragment)
// w1a[ch][16]; w3b[c][lh][l31=t][8] lane-coalesced
__global__ __launch_bounds__(256) void prep_kernel(
    const float* __restrict__ w2, const float* __restrict__ w1,
    const float* __restrict__ w3, short* __restrict__ w2b,
    short* __restrict__ w1a, short* __restrict__ w3b) {
  int idx = blockIdx.x * 256 + threadIdx.x;
  if (idx < 36864) {
    int cob = idx / 18432, r = idx % 18432;
    int t = r / 2048, r2 = r & 2047;
    int c = r2 >> 9, lh = (r2 >> 8) & 1, l31 = (r2 >> 3) & 31, j = r2 & 7;
    int co = cob * 32 + l31, ci = c * 16 + 8 * lh + j;
    w2b[idx] = f2bf(w2[(co * 64 + ci) * 9 + t]);
  } else if (idx < 37888) {
    int j = idx - 36864;
    int ch = j >> 4, t = j & 15;
    w1a[j] = (t < 9) ? f2bf(w1[ch * 9 + t]) : (short)0;
  } else if (idx < 39936) {
    int q = idx - 37888;
    int c = q >> 9, lh = (q >> 8) & 1, l31 = (q >> 3) & 31, j = q & 7;
    int t = l31, ci = c * 16 + 8 * lh + j;
    w3b[q] = (t < 9) ? f2bf(w3[ci * 9 + t]) : (short)0;
  }
}

// ---------------- fused 3x Jacobi + residual ---------------------------
__global__ __launch_bounds__(256) void jac3_kernel(
    const float* __restrict__ uin, const float* __restrict__ f,
    float* __restrict__ u1o, float* __restrict__ u2o,
    float* __restrict__ u3o, float* __restrict__ res_ws) {
  __shared__ float As[576];   // 24x24
  __shared__ float Bs[484];   // 22x22
  __shared__ float Fs[484];   // 22x22, coords = (y0-3+i, x0-3+j)
  int tid = threadIdx.x;
  int bl = blockIdx.x >> 6, tile = blockIdx.x & 63;
  int y0 = (tile >> 3) << 4, x0 = (tile & 7) << 4;
  const float* ub = uin + ((size_t)bl << 14);
  const float* fb = f + ((size_t)bl << 14);
  for (int i = tid; i < 576; i += 256) {
    int uy = i / 24, ux = i % 24;
    As[i] = ub[(((y0 + uy - 4) & NMASK) << 7) + ((x0 + ux - 4) & NMASK)];
  }
  for (int i = tid; i < 484; i += 256) {
    int uy = i / 22, ux = i % 22;
    Fs[i] = fb[(((y0 + uy - 3) & NMASK) << 7) + ((x0 + ux - 3) & NMASK)];
  }
  __syncthreads();
  for (int i = tid; i < 484; i += 256) {
    int yy = i / 22, xx = i % 22;
    float uc = As[(yy + 1) * 24 + xx + 1];
    float ns = As[yy * 24 + xx + 1] + As[(yy + 2) * 24 + xx + 1]
             + As[(yy + 1) * 24 + xx] + As[(yy + 1) * 24 + xx + 2];
    Bs[i] = uc + Fs[i] * (1.f / 65536.f) + (ns - 4.f * uc) * 0.25f;
  }
  __syncthreads();
  {
    int y = tid >> 4, x = tid & 15;
    u1o[((size_t)bl << 14) + ((y0 + y) << 7) + x0 + x] = Bs[(y + 3) * 22 + x + 3];
  }
  for (int i = tid; i < 400; i += 256) {
    int yy = i / 20, xx = i % 20;
    float uc = Bs[(yy + 1) * 22 + xx + 1];
    float ns = Bs[yy * 22 + xx + 1] + Bs[(yy + 2) * 22 + xx + 1]
             + Bs[(yy + 1) * 22 + xx] + Bs[(yy + 1) * 22 + xx + 2];
    As[i] = uc + Fs[(yy + 1) * 22 + xx + 1] * (1.f / 65536.f)
          + (ns - 4.f * uc) * 0.25f;
  }
  __syncthreads();
  {
    int y = tid >> 4, x = tid & 15;
    u2o[((size_t)bl << 14) + ((y0 + y) << 7) + x0 + x] = As[(y + 2) * 20 + x + 2];
  }
  for (int i = tid; i < 324; i += 256) {
    int yy = i / 18, xx = i % 18;
    float uc = As[(yy + 1) * 20 + xx + 1];
    float ns = As[yy * 20 + xx + 1] + As[(yy + 2) * 20 + xx + 1]
             + As[(yy + 1) * 20 + xx] + As[(yy + 1) * 20 + xx + 2];
    Bs[i] = uc + Fs[(yy + 2) * 22 + xx + 2] * (1.f / 65536.f)
          + (ns - 4.f * uc) * 0.25f;
  }
  __syncthreads();
  {
    int y = tid >> 4, x = tid & 15;
    size_t gi = ((size_t)bl << 14) + ((y0 + y) << 7) + x0 + x;
    float uc = Bs[(y + 1) * 18 + x + 1];
    u3o[gi] = uc;
    float ns = Bs[y * 18 + x + 1] + Bs[(y + 2) * 18 + x + 1]
             + Bs[(y + 1) * 18 + x] + Bs[(y + 1) * 18 + x + 2];
    res_ws[gi] = Fs[(y + 3) * 22 + x + 3] + (ns - 4.f * uc) * 16384.f;
  }
}

// ---------------- fused conv1 + conv2 + depthwise-conv3 (all MFMA) -----
// 256 threads (4 waves); wave wv owns px [wv*64, wv*64+64) (nt=2), all 64 co.
// conv2 weight loads are depth-1 software-pipelined over t; t=0 stage is
// issued before the conv1 barrier so its L2 latency hides under conv1.
__global__ __launch_bounds__(256, 3) void mlstep_a(
    const float* __restrict__ res_ws,
    const short* __restrict__ w1a, const float* __restrict__ b1v,
    const short* __restrict__ w2b, const float* __restrict__ b2v,
    const short* __restrict__ w3b, float* __restrict__ D_ws,
    int b0, int BC) {
  __shared__ __align__(16) short h1g[8 * 324 * 8];  // reused as h2t [8][256][8]
  __shared__ float res_s[400];                      // 20x20, halo 2
  int tid = threadIdx.x;
  int bl = blockIdx.x >> 6;
  int tile = blockIdx.x & 63;
  int y0 = (tile >> 3) << 4, x0 = (tile & 7) << 4;
  const float* rb = res_ws + ((size_t)(b0 + bl) << 14);

  for (int i = tid; i < 400; i += 256) {
    int ry = i / 20, rx = i % 20;
    res_s[i] = rb[(((y0 + ry - 2) & NMASK) << 7) + ((x0 + rx - 2) & NMASK)];
  }

  int lane = tid & 63, wv = tid >> 6;  // wv in 0..3
  int l31 = lane & 31, lh = lane >> 5;

  // ---- pre-issue conv2 t=0 weight stage (L2 latency hides under conv1) --
  const char* wb = (const char*)w2b + lane * 16;
  short8 a0[4], a1[4];
#pragma unroll
  for (int c = 0; c < 4; ++c) {
    a0[c] = *reinterpret_cast<const short8*>(wb + c * 1024);
    a1[c] = *reinterpret_cast<const short8*>(wb + (36 + c) * 1024);
  }
  __syncthreads();

  // conv1 via MFMA (11 pos-groups over 4 waves); B-frag built in registers
  {
    short8 a1lo = *reinterpret_cast<const short8*>(&w1a[l31 * 16 + 8 * lh]);
    short8 a1hi = *reinterpret_cast<const short8*>(&w1a[(32 + l31) * 16 + 8 * lh]);
    for (int g = wv; g < 11; g += 4) {
      int pos = g * 32 + l31;
      short8 bf = {};
      if (pos < 324) {
        int yy = pos / 18, xx = pos % 18;
        if (lh == 0) {
#pragma unroll
          for (int t = 0; t < 8; ++t)
            bf[t] = f2bf(res_s[(yy + t / 3) * 20 + xx + t % 3]);
        } else {
          bf[0] = f2bf(res_s[(yy + 2) * 20 + xx + 2]);
        }
      }
      f32x16 acc0, acc1;
#pragma unroll
      for (int r = 0; r < 16; ++r) { acc0[r] = 0.f; acc1[r] = 0.f; }
      acc0 = __builtin_amdgcn_mfma_f32_32x32x16_bf16(a1lo, bf, acc0, 0, 0, 0);
      acc1 = __builtin_amdgcn_mfma_f32_32x32x16_bf16(a1hi, bf, acc1, 0, 0, 0);
      if (pos < 324) {
#pragma unroll
        for (int q = 0; q < 4; ++q) {
          f32x4 bv0 = *reinterpret_cast<const f32x4*>(&b1v[8 * q + 4 * lh]);
          f32x4 bv1 = *reinterpret_cast<const f32x4*>(&b1v[32 + 8 * q + 4 * lh]);
          short4v o0, o1;
#pragma unroll
          for (int j = 0; j < 4; ++j) {
            float v0 = acc0[4 * q + j] + bv0[j];
            float v1 = acc1[4 * q + j] + bv1[j];
            o0[j] = f2bf(v0 > 0.f ? v0 : 0.f);
            o1[j] = f2bf(v1 > 0.f ? v1 : 0.f);
          }
          *reinterpret_cast<short4v*>(
              (char*)h1g + (q * 324 + pos) * 16 + 8 * lh) = o0;
          *reinterpret_cast<short4v*>(
              (char*)h1g + ((4 + q) * 324 + pos) * 16 + 8 * lh) = o1;
        }
      }
    }
  }
  __syncthreads();

  // conv2: 2 cob x 2 nt per wave; depth-1 weight pipeline over t
  {
    const char* hb[2];
#pragma unroll
    for (int nt = 0; nt < 2; ++nt) {
      int px = (wv << 6) + (nt << 5) + l31;
      int pos0 = (px >> 4) * 18 + (px & 15);
      hb[nt] = (const char*)h1g + lh * 5184 + pos0 * 16;
    }
    f32x16 acc[2][2];  // [cob][nt]
#pragma unroll
    for (int cb = 0; cb < 2; ++cb)
#pragma unroll
      for (int nt = 0; nt < 2; ++nt)
#pragma unroll
        for (int r = 0; r < 16; ++r) acc[cb][nt][r] = 0.f;
#pragma unroll
    for (int t = 0; t < 9; ++t) {
      short8 a0n[4], a1n[4];
      if (t < 8) {
#pragma unroll
        for (int c = 0; c < 4; ++c) {
          a0n[c] = *reinterpret_cast<const short8*>(
              wb + ((t + 1) * 4 + c) * 1024);
          a1n[c] = *reinterpret_cast<const short8*>(
              wb + ((10 + t) * 4 + c) * 1024);
        }
      }
      int toff = ((t / 3) * 18 + (t % 3)) * 16;
      __builtin_amdgcn_s_setprio(1);
#pragma unroll
      for (int c = 0; c < 4; ++c) {
#pragma unroll
        for (int nt = 0; nt < 2; ++nt) {
          short8 bf = *reinterpret_cast<const short8*>(
              hb[nt] + c * 10368 + toff);
          acc[0][nt] = __builtin_amdgcn_mfma_f32_32x32x16_bf16(a0[c], bf,
                                                               acc[0][nt], 0, 0, 0);
          acc[1][nt] = __builtin_amdgcn_mfma_f32_32x32x16_bf16(a1[c], bf,
                                                               acc[1][nt], 0, 0, 0);
        }
      }
      __builtin_amdgcn_s_setprio(0);
      if (t < 8) {
#pragma unroll
        for (int c = 0; c < 4; ++c) { a0[c] = a0n[c]; a1[c] = a1n[c]; }
      }
    }
    __syncthreads();  // conv2 reads of h1g done -> reuse as h2t

    // h2 (ReLU+bias, bf16) -> LDS cg-major [cg][px][8]
    short* h2t = h1g;
#pragma unroll
    for (int nt = 0; nt < 2; ++nt) {
      int px = (wv << 6) + (nt << 5) + l31;
#pragma unroll
      for (int cb = 0; cb < 2; ++cb) {
#pragma unroll
        for (int q = 0; q < 4; ++q) {
          int ch0 = cb * 32 + 8 * q + 4 * lh;
          f32x4 bv = *reinterpret_cast<const f32x4*>(&b2v[ch0]);
          short4v o;
#pragma unroll
          for (int j = 0; j < 4; ++j) {
            float v = acc[cb][nt][4 * q + j] + bv[j];
            o[j] = f2bf(v > 0.f ? v : 0.f);
          }
          int cg = cb * 4 + q;
          *reinterpret_cast<short4v*>(&h2t[(cg * 256 + px) * 8 + 4 * lh]) = o;
        }
      }
    }
    // depthwise conv3 — wave-local px, no barrier needed
    short8 af3[4];
#pragma unroll
    for (int c = 0; c < 4; ++c)
      af3[c] = *reinterpret_cast<const short8*>(
          (const char*)w3b + c * 1024 + lane * 16);
#pragma unroll
    for (int nt = 0; nt < 2; ++nt) {
      int pxb = (wv << 6) + (nt << 5);
      f32x16 d;
#pragma unroll
      for (int r = 0; r < 16; ++r) d[r] = 0.f;
      __builtin_amdgcn_s_setprio(1);
#pragma unroll
      for (int c = 0; c < 4; ++c) {
        short8 bf = *reinterpret_cast<const short8*>(
            (const char*)h2t + ((2 * c + lh) * 256 + pxb + l31) * 16);
        d = __builtin_amdgcn_mfma_f32_32x32x16_bf16(af3[c], bf, d, 0, 0, 0);
      }
      __builtin_amdgcn_s_setprio(0);
      int px = pxb + l31;
      int gpx = ((y0 + (px >> 4)) << 7) + x0 + (px & 15);
      if (lh == 0) {
#pragma unroll
        for (int r = 0; r < 4; ++r)
          D_ws[((size_t)(r * BC + bl) << 14) + gpx] = d[r];
        D_ws[((size_t)(8 * BC + bl) << 14) + gpx] = d[4];
      } else {
#pragma unroll
        for (int r = 0; r < 4; ++r)
          D_ws[((size_t)((4 + r) * BC + bl) << 14) + gpx] = d[r];
      }
    }
  }
}

// ---------------- conv3 shift-sum + u update (memory-bound) -------------
__global__ __launch_bounds__(256) void mlstep_b(
    const float* __restrict__ D_ws, const float* __restrict__ b3,
    const float* __restrict__ uprev, float* __restrict__ uout,
    int b0, int BC) {
  int idx = blockIdx.x * 256 + threadIdx.x;
  int bl = idx >> 14;
  int rem = idx & (SPAT - 1);
  int y = rem >> 7, x = rem & NMASK;
  float acc = b3[0];
#pragma unroll
  for (int t = 0; t < 9; ++t) {
    int yy = (y + t / 3 - 1) & NMASK;
    int xx = (x + t % 3 - 1) & NMASK;
    acc += D_ws[((size_t)(t * BC + bl) << 14) + (yy << 7) + xx];
  }
  size_t g = ((size_t)(b0 + bl) << 14) + rem;
  uout[g] = uprev[g] + acc;
}

// ---------------- routing scores ----------------------------------------
__global__ void scores_kernel(float* __restrict__ s) {
  int i = blockIdx.x * 256 + threadIdx.x;
  if (i < 8 * BS * 2) {
    int it = i >> 6;
    int k = i & 1;
    bool ml = (it & 3) == 3;
    s[i] = ml ? (float)k : (float)(1 - k);
  }
}

extern "C" void kernel_launch(void* const* d_in, const int* in_sizes, int n_in,
                              void* d_out, int out_size, void* d_ws,
                              size_t ws_size, hipStream_t stream) {
  (void)in_sizes; (void)n_in; (void)out_size;
  const float* f  = (const float*)d_in[0];
  const float* u0 = (const float*)d_in[1];
  const float* w1 = (const float*)d_in[2];
  const float* b1 = (const float*)d_in[3];
  const float* w2 = (const float*)d_in[4];
  const float* b2 = (const float*)d_in[5];
  const float* w3 = (const float*)d_in[6];
  const float* b3 = (const float*)d_in[7];

  float* preds  = (float*)d_out;                  // [8][32][128][128]
  float* scores = preds + (size_t)8 * BS * SPAT;  // [8][32][2]

  short* w2b = (short*)d_ws;                       // 73728 B
  short* w1a = w2b + 36864;                        // 2048 B
  short* w3b = w1a + 1024;                         // 4096 B
  float* res_ws = (float*)(w3b + 2048);            // 2 MB
  float* D_ws = res_ws + (size_t)BS * SPAT;        // 9*BC*64KB
  size_t fixed = (size_t)(36864 + 1024 + 2048) * 2 + (size_t)BS * SPAT * 4;
  size_t avail = ws_size > fixed ? ws_size - fixed : 0;
  int BC = 32;
  while (BC > 1 && (size_t)BC * ((size_t)9 * SPAT * 4) > avail) BC >>= 1;

  prep_kernel<<<156, 256, 0, stream>>>(w2, w1, w3, w2b, w1a, w3b);

  for (int p = 0; p < 2; ++p) {
    int it = 4 * p;
    const float* up = (p == 0) ? u0 : preds + (size_t)3 * BS * SPAT;
    float* u1o = preds + (size_t)(it + 0) * BS * SPAT;
    float* u2o = preds + (size_t)(it + 1) * BS * SPAT;
    float* u3o = preds + (size_t)(it + 2) * BS * SPAT;
    float* umo = preds + (size_t)(it + 3) * BS * SPAT;
    jac3_kernel<<<BS * 64, 256, 0, stream>>>(up, f, u1o, u2o, u3o, res_ws);
    for (int b0 = 0; b0 < BS; b0 += BC) {
      mlstep_a<<<BC * 64, 256, 0, stream>>>(res_ws, w1a, b1, w2b, b2, w3b,
                                            D_ws, b0, BC);
      mlstep_b<<<BC * SPAT / 256, 256, 0, stream>>>(D_ws, b3, u3o, umo, b0, BC);
    }
  }
  scores_kernel<<<2, 256, 0, stream>>>(scores);
}